// Round 1
// 480.121 us; speedup vs baseline: 1.4352x; 1.4352x over previous
//
#include <hip/hip_runtime.h>

// LoRA linear, two-kernel split: t = x @ A^T (16384x16), out = t @ B^T (16384x4096).
// t lives in a static __device__ buffer (1 MiB); same-stream launch order gives
// K1 -> K2 visibility (implicit L2 flush between dispatches).
//
// R2 theory: the fused kernel was latency-bound (VALUBusy 12%, occ 22%) from
// 20 VMEM requests/iter (16 of them A-loads from L2), and moved 1.52 GB HBM
// (FETCH 3.3x, WRITE 2.4x ideal). K1 stages A in LDS so the inner loop is
// 4 streaming x-loads only. K2 uses PLAIN float4 stores (not nontemporal) to
// let full lines assemble in L2 and write back once -- testing the theory that
// nt 16B stores caused partial-sector RMW write amplification.

typedef float f4 __attribute__((ext_vector_type(4)));

#define M_TOTAL 16384
#define K_DIM 4096
#define N_DIM 4096
#define R_DIM 16

__device__ float t_buf[M_TOTAL * R_DIM];   // 1 MiB intermediate

// ---------------- Kernel 1: t = x @ A^T ----------------
// Block: 256 threads = 4 waves, 4 rows/wave -> 16 rows/block, 1024 blocks.
// A staged in LDS in [16][512] chunks (32 KiB): inner loop has only the 4
// nontemporal x-loads as VMEM; A comes from LDS (conflict-free b128 reads).

#define KC 512                     // K-chunk (floats) staged in LDS

__global__ __launch_bounds__(256, 2)
void lora_phase1(const float* __restrict__ x, const float* __restrict__ A)
{
    __shared__ float A_lds[R_DIM][KC];       // 32 KiB

    const int tid  = threadIdx.x;
    const int wave = tid >> 6;
    const int lane = tid & 63;
    const int wave_row0 = blockIdx.x * 16 + wave * 4;

    float acc[4][R_DIM];
    #pragma unroll
    for (int w = 0; w < 4; ++w)
        #pragma unroll
        for (int r = 0; r < R_DIM; ++r) acc[w][r] = 0.0f;

    const f4* xr0 = reinterpret_cast<const f4*>(x + (size_t)(wave_row0 + 0) * K_DIM);
    const f4* xr1 = reinterpret_cast<const f4*>(x + (size_t)(wave_row0 + 1) * K_DIM);
    const f4* xr2 = reinterpret_cast<const f4*>(x + (size_t)(wave_row0 + 2) * K_DIM);
    const f4* xr3 = reinterpret_cast<const f4*>(x + (size_t)(wave_row0 + 3) * K_DIM);

    #pragma unroll 1
    for (int c = 0; c < K_DIM / KC; ++c) {
        __syncthreads();             // previous chunk's LDS reads done
        // Stage A[0:16][c*KC .. c*KC+KC): wave w stages rows 4w..4w+3,
        // 2 x 1KB (64 lanes * 16B) per row. Plain loads: A is L2/L3-hot.
        #pragma unroll
        for (int i = 0; i < 8; ++i) {
            const int r    = wave * 4 + (i >> 1);
            const int half = i & 1;
            f4 v = *reinterpret_cast<const f4*>(
                       A + (size_t)r * K_DIM + c * KC + half * 256 + lane * 4);
            *reinterpret_cast<f4*>(&A_lds[r][half * 256 + lane * 4]) = v;
        }
        __syncthreads();

        #pragma unroll
        for (int s = 0; s < 2; ++s) {
            const int cidx = c * (KC / 4) + s * 64 + lane;   // f4 index in row
            f4 xv0 = __builtin_nontemporal_load(&xr0[cidx]);
            f4 xv1 = __builtin_nontemporal_load(&xr1[cidx]);
            f4 xv2 = __builtin_nontemporal_load(&xr2[cidx]);
            f4 xv3 = __builtin_nontemporal_load(&xr3[cidx]);
            #pragma unroll
            for (int r = 0; r < R_DIM; ++r) {
                f4 av = *reinterpret_cast<const f4*>(&A_lds[r][s * 256 + lane * 4]);
                acc[0][r] += xv0[0] * av[0] + xv0[1] * av[1] + xv0[2] * av[2] + xv0[3] * av[3];
                acc[1][r] += xv1[0] * av[0] + xv1[1] * av[1] + xv1[2] * av[2] + xv1[3] * av[3];
                acc[2][r] += xv2[0] * av[0] + xv2[1] * av[1] + xv2[2] * av[2] + xv2[3] * av[3];
                acc[3][r] += xv3[0] * av[0] + xv3[1] * av[1] + xv3[2] * av[2] + xv3[3] * av[3];
            }
        }
    }

    // Wave-wide butterfly reduction of all 64 partials.
    #pragma unroll
    for (int w = 0; w < 4; ++w) {
        #pragma unroll
        for (int r = 0; r < R_DIM; ++r) {
            float v = acc[w][r];
            v += __shfl_xor(v, 32, 64);
            v += __shfl_xor(v, 16, 64);
            v += __shfl_xor(v,  8, 64);
            v += __shfl_xor(v,  4, 64);
            v += __shfl_xor(v,  2, 64);
            v += __shfl_xor(v,  1, 64);
            acc[w][r] = v;
        }
    }
    if (lane == 0) {
        #pragma unroll
        for (int w = 0; w < 4; ++w) {
            float* tp = t_buf + (size_t)(wave_row0 + w) * R_DIM;
            #pragma unroll
            for (int rc = 0; rc < 4; ++rc) {
                f4 v = { acc[w][rc * 4 + 0], acc[w][rc * 4 + 1],
                         acc[w][rc * 4 + 2], acc[w][rc * 4 + 3] };
                *reinterpret_cast<f4*>(tp + rc * 4) = v;
            }
        }
    }
}

// ---------------- Kernel 2: out = t @ B^T ----------------
// Block: 256 threads, tile = 64 rows x 1024 cols (grid 1024). Each thread owns
// 4 consecutive output cols (B rows in 64 regs), iterates 64 t-rows from LDS
// broadcast. Plain float4 stores: full-line writeback via L2, written once.

#define P2_ROWS 64

__global__ __launch_bounds__(256, 2)
void lora_phase2(const float* __restrict__ Bm, float* __restrict__ out)
{
    __shared__ float t_lds[P2_ROWS][R_DIM];   // 4 KiB

    const int tid  = threadIdx.x;
    const int row0 = (blockIdx.x >> 2) * P2_ROWS;
    const int o0   = (blockIdx.x & 3) * 1024 + tid * 4;

    // Stage this block's 64 t-rows (1024 floats) with one f4 per thread.
    reinterpret_cast<f4*>(&t_lds[0][0])[tid] =
        reinterpret_cast<const f4*>(t_buf + (size_t)row0 * R_DIM)[tid];

    // B rows for my 4 output cols, in registers (L2-hot).
    float br[4][R_DIM];
    #pragma unroll
    for (int oo = 0; oo < 4; ++oo) {
        const f4* bp = reinterpret_cast<const f4*>(Bm + (size_t)(o0 + oo) * R_DIM);
        #pragma unroll
        for (int rc = 0; rc < 4; ++rc) {
            f4 b4 = bp[rc];
            br[oo][rc * 4 + 0] = b4[0];
            br[oo][rc * 4 + 1] = b4[1];
            br[oo][rc * 4 + 2] = b4[2];
            br[oo][rc * 4 + 3] = b4[3];
        }
    }
    __syncthreads();

    #pragma unroll 4
    for (int m = 0; m < P2_ROWS; ++m) {
        float tv[R_DIM];
        const f4* tp = reinterpret_cast<const f4*>(&t_lds[m][0]);
        #pragma unroll
        for (int rc = 0; rc < 4; ++rc) {
            f4 t4 = tp[rc];                  // LDS broadcast (same addr, free)
            tv[rc * 4 + 0] = t4[0];
            tv[rc * 4 + 1] = t4[1];
            tv[rc * 4 + 2] = t4[2];
            tv[rc * 4 + 3] = t4[3];
        }
        f4 oa = {0.0f, 0.0f, 0.0f, 0.0f};
        #pragma unroll
        for (int r = 0; r < R_DIM; ++r) {
            oa[0] += tv[r] * br[0][r];
            oa[1] += tv[r] * br[1][r];
            oa[2] += tv[r] * br[2][r];
            oa[3] += tv[r] * br[3][r];
        }
        // PLAIN store (A/B test vs nontemporal): assemble full lines in L2.
        *reinterpret_cast<f4*>(out + (size_t)(row0 + m) * N_DIM + o0) = oa;
    }
}

extern "C" void kernel_launch(void* const* d_in, const int* in_sizes, int n_in,
                              void* d_out, int out_size, void* d_ws, size_t ws_size,
                              hipStream_t stream) {
    const float* x  = (const float*)d_in[0];   // [4,4096,4096]
    const float* A  = (const float*)d_in[1];   // [16,4096]
    const float* Bm = (const float*)d_in[2];   // [4096,16]
    float* out = (float*)d_out;                // [4,4096,4096]

    lora_phase1<<<dim3(M_TOTAL / 16), dim3(256), 0, stream>>>(x, A);
    lora_phase2<<<dim3((M_TOTAL / P2_ROWS) * 4), dim3(256), 0, stream>>>(Bm, out);
}

// Round 2
// 461.127 us; speedup vs baseline: 1.4943x; 1.0412x over previous
//
#include <hip/hip_runtime.h>

// LoRA linear, two-kernel split: t = x @ A^T (16384x16), out = t @ B^T (16384x4096).
// t lives in a static __device__ buffer (1 MiB); same-stream ordering gives K1->K2
// visibility (verified: round-1 passed).
//
// R3 change (phase 1 ONLY, phase 2 identical to round 1 for attribution):
// software-pipelined A staging. Round-1 phase 1 had 2 barriers per chunk with the
// A-from-L2 staging latency fully exposed between them. Now: per 256-float chunk,
// issue next-chunk A loads (to regs) + next-chunk nt x-loads, compute current
// chunk from LDS buf[c&1], then ds_write staged regs to buf[c^1] (their vmcnt
// wait lands after a full compute phase) and one barrier. 2x16 KiB LDS dbuf.

typedef float f4 __attribute__((ext_vector_type(4)));

#define M_TOTAL 16384
#define K_DIM 4096
#define N_DIM 4096
#define R_DIM 16

__device__ float t_buf[M_TOTAL * R_DIM];   // 1 MiB intermediate

// ---------------- Kernel 1: t = x @ A^T ----------------
// 256 threads = 4 waves, 4 rows/wave -> 16 rows/block, 1024 blocks.
// Chunk = 256 floats of K. Per chunk per wave: 4 nt x-loads + 16 LDS f4 reads
// + 256 FMA (~550 cy). Stage regs: wave w stages A rows {w,4+w,8+w,12+w}.

#define KC 256
#define NCHUNK (K_DIM / KC)   // 16

__global__ __launch_bounds__(256, 2)
void lora_phase1(const float* __restrict__ x, const float* __restrict__ A)
{
    __shared__ float A_lds[2][R_DIM][KC];    // 2 x 16 KiB

    const int tid  = threadIdx.x;
    const int wave = tid >> 6;
    const int lane = tid & 63;
    const int wave_row0 = blockIdx.x * 16 + wave * 4;

    float acc[4][R_DIM];
    #pragma unroll
    for (int w = 0; w < 4; ++w)
        #pragma unroll
        for (int r = 0; r < R_DIM; ++r) acc[w][r] = 0.0f;

    const f4* xr0 = reinterpret_cast<const f4*>(x + (size_t)(wave_row0 + 0) * K_DIM);
    const f4* xr1 = reinterpret_cast<const f4*>(x + (size_t)(wave_row0 + 1) * K_DIM);
    const f4* xr2 = reinterpret_cast<const f4*>(x + (size_t)(wave_row0 + 2) * K_DIM);
    const f4* xr3 = reinterpret_cast<const f4*>(x + (size_t)(wave_row0 + 3) * K_DIM);

    // Prologue: stage chunk 0 into buf 0; prefetch x chunk 0.
    f4 sreg[4];
    #pragma unroll
    for (int p = 0; p < 4; ++p)
        sreg[p] = *reinterpret_cast<const f4*>(A + (size_t)(p * 4 + wave) * K_DIM + lane * 4);
    #pragma unroll
    for (int p = 0; p < 4; ++p)
        *reinterpret_cast<f4*>(&A_lds[0][p * 4 + wave][lane * 4]) = sreg[p];

    f4 xv0 = __builtin_nontemporal_load(&xr0[lane]);
    f4 xv1 = __builtin_nontemporal_load(&xr1[lane]);
    f4 xv2 = __builtin_nontemporal_load(&xr2[lane]);
    f4 xv3 = __builtin_nontemporal_load(&xr3[lane]);
    __syncthreads();

    #pragma unroll 1
    for (int c = 0; c < NCHUNK; ++c) {
        const int cur = c & 1;
        const bool more = (c + 1 < NCHUNK);
        f4 xn0, xn1, xn2, xn3;
        if (more) {
            // Issue next-chunk loads NOW; consumed after the next barrier.
            const int nidx = (c + 1) * 64 + lane;
            xn0 = __builtin_nontemporal_load(&xr0[nidx]);
            xn1 = __builtin_nontemporal_load(&xr1[nidx]);
            xn2 = __builtin_nontemporal_load(&xr2[nidx]);
            xn3 = __builtin_nontemporal_load(&xr3[nidx]);
            #pragma unroll
            for (int p = 0; p < 4; ++p)
                sreg[p] = *reinterpret_cast<const f4*>(
                    A + (size_t)(p * 4 + wave) * K_DIM + (c + 1) * KC + lane * 4);
        }

        // Compute current chunk from LDS (stride-1 b128 reads: 2-way alias, free).
        #pragma unroll
        for (int r = 0; r < R_DIM; ++r) {
            f4 av = *reinterpret_cast<const f4*>(&A_lds[cur][r][lane * 4]);
            acc[0][r] += xv0[0] * av[0] + xv0[1] * av[1] + xv0[2] * av[2] + xv0[3] * av[3];
            acc[1][r] += xv1[0] * av[0] + xv1[1] * av[1] + xv1[2] * av[2] + xv1[3] * av[3];
            acc[2][r] += xv2[0] * av[0] + xv2[1] * av[1] + xv2[2] * av[2] + xv2[3] * av[3];
            acc[3][r] += xv3[0] * av[0] + xv3[1] * av[1] + xv3[2] * av[2] + xv3[3] * av[3];
        }

        if (more) {
            // Stage-load vmcnt wait lands here, one full compute phase after issue.
            #pragma unroll
            for (int p = 0; p < 4; ++p)
                *reinterpret_cast<f4*>(&A_lds[cur ^ 1][p * 4 + wave][lane * 4]) = sreg[p];
            xv0 = xn0; xv1 = xn1; xv2 = xn2; xv3 = xn3;
        }
        __syncthreads();
    }

    // Wave-wide butterfly reduction of all 64 partials.
    #pragma unroll
    for (int w = 0; w < 4; ++w) {
        #pragma unroll
        for (int r = 0; r < R_DIM; ++r) {
            float v = acc[w][r];
            v += __shfl_xor(v, 32, 64);
            v += __shfl_xor(v, 16, 64);
            v += __shfl_xor(v,  8, 64);
            v += __shfl_xor(v,  4, 64);
            v += __shfl_xor(v,  2, 64);
            v += __shfl_xor(v,  1, 64);
            acc[w][r] = v;
        }
    }
    if (lane == 0) {
        #pragma unroll
        for (int w = 0; w < 4; ++w) {
            float* tp = t_buf + (size_t)(wave_row0 + w) * R_DIM;
            #pragma unroll
            for (int rc = 0; rc < 4; ++rc) {
                f4 v = { acc[w][rc * 4 + 0], acc[w][rc * 4 + 1],
                         acc[w][rc * 4 + 2], acc[w][rc * 4 + 3] };
                *reinterpret_cast<f4*>(tp + rc * 4) = v;
            }
        }
    }
}

// ---------------- Kernel 2: out = t @ B^T (unchanged from round 1) ----------------
// 256 threads, tile = 64 rows x 1024 cols (grid 1024). Thread owns 4 output cols
// (B rows in 64 regs), iterates 64 t-rows from LDS broadcast. Plain f4 stores.

#define P2_ROWS 64

__global__ __launch_bounds__(256, 2)
void lora_phase2(const float* __restrict__ Bm, float* __restrict__ out)
{
    __shared__ float t_lds[P2_ROWS][R_DIM];   // 4 KiB

    const int tid  = threadIdx.x;
    const int row0 = (blockIdx.x >> 2) * P2_ROWS;
    const int o0   = (blockIdx.x & 3) * 1024 + tid * 4;

    // Stage this block's 64 t-rows (1024 floats) with one f4 per thread.
    reinterpret_cast<f4*>(&t_lds[0][0])[tid] =
        reinterpret_cast<const f4*>(t_buf + (size_t)row0 * R_DIM)[tid];

    // B rows for my 4 output cols, in registers (L2-hot).
    float br[4][R_DIM];
    #pragma unroll
    for (int oo = 0; oo < 4; ++oo) {
        const f4* bp = reinterpret_cast<const f4*>(Bm + (size_t)(o0 + oo) * R_DIM);
        #pragma unroll
        for (int rc = 0; rc < 4; ++rc) {
            f4 b4 = bp[rc];
            br[oo][rc * 4 + 0] = b4[0];
            br[oo][rc * 4 + 1] = b4[1];
            br[oo][rc * 4 + 2] = b4[2];
            br[oo][rc * 4 + 3] = b4[3];
        }
    }
    __syncthreads();

    #pragma unroll 4
    for (int m = 0; m < P2_ROWS; ++m) {
        float tv[R_DIM];
        const f4* tp = reinterpret_cast<const f4*>(&t_lds[m][0]);
        #pragma unroll
        for (int rc = 0; rc < 4; ++rc) {
            f4 t4 = tp[rc];                  // same addr across wave: LDS broadcast
            tv[rc * 4 + 0] = t4[0];
            tv[rc * 4 + 1] = t4[1];
            tv[rc * 4 + 2] = t4[2];
            tv[rc * 4 + 3] = t4[3];
        }
        f4 oa = {0.0f, 0.0f, 0.0f, 0.0f};
        #pragma unroll
        for (int r = 0; r < R_DIM; ++r) {
            oa[0] += tv[r] * br[0][r];
            oa[1] += tv[r] * br[1][r];
            oa[2] += tv[r] * br[2][r];
            oa[3] += tv[r] * br[3][r];
        }
        // PLAIN store: assemble full 128B lines in L2, write back once.
        *reinterpret_cast<f4*>(out + (size_t)(row0 + m) * N_DIM + o0) = oa;
    }
}

extern "C" void kernel_launch(void* const* d_in, const int* in_sizes, int n_in,
                              void* d_out, int out_size, void* d_ws, size_t ws_size,
                              hipStream_t stream) {
    const float* x  = (const float*)d_in[0];   // [4,4096,4096]
    const float* A  = (const float*)d_in[1];   // [16,4096]
    const float* Bm = (const float*)d_in[2];   // [4096,16]
    float* out = (float*)d_out;                // [4,4096,4096]

    lora_phase1<<<dim3(M_TOTAL / 16), dim3(256), 0, stream>>>(x, A);
    lora_phase2<<<dim3((M_TOTAL / P2_ROWS) * 4), dim3(256), 0, stream>>>(Bm, out);
}